// Round 8
// baseline (292.428 us; speedup 1.0000x reference)
//
#include <hip/hip_runtime.h>
#include <hip/hip_bf16.h>
#include <math.h>

#define NV   5023
#define N3   15069
#define NB   2048
#define NTIL 79            // ceil(N3/192) column tiles
#define NPAD (NTIL*192)    // 15168 padded B rows

// ---- workspace byte offsets ----
#define WS_JD_B   0          // 2272 floats
#define WS_ATR_B  9216       // 2048*60*4  = 491520
#define WS_AB_B   795648     // 2048*192*2 = 786432 (bf16 A)
#define WS_BB_B   1582080    // 15168*192*2 = 5824512 (bf16 B, n-major, padded)

// k_prep block ranges
#define GP_J 126             // jdirs slices
#define GP_S 1067            // sdirs->B cols 0..143 (NPAD*18 int4 / 256)
#define GP_P 237             // pose cols 144..191 (NPAD/64)

typedef __attribute__((ext_vector_type(8))) short short8;
typedef __attribute__((ext_vector_type(4))) float floatx4;

static __device__ __forceinline__ unsigned short f2bf(float x) {
    union { __hip_bfloat16 h; unsigned short s; } u;
    u.h = __float2bfloat16(x);
    return u.s;
}
static __device__ __forceinline__ unsigned int pk2(float a, float b) {
    return (unsigned int)f2bf(a) | ((unsigned int)f2bf(b) << 16);
}

// lgkmcnt-only barrier: cross-thread LDS ordering without draining the
// vmem store queue -- stores stay in flight across phases.
#define BAR_LGKM() do { \
    asm volatile("s_waitcnt lgkmcnt(0)" ::: "memory"); \
    __builtin_amdgcn_s_barrier(); \
    asm volatile("" ::: "memory"); \
} while (0)

// ---------------- fused prep: jdirs | B cols 0..143 | B cols 144..191 ----------------
__global__ void k_prep(const float* __restrict__ Jreg,   // [5][NV]
                       const float* __restrict__ sdirs,  // [NV][450] == [N3][150]
                       const float* __restrict__ vt,     // [NV][3]
                       const float* __restrict__ pdirs,  // [36][N3]
                       char* __restrict__ ws) {
    __shared__ float JregL[200];      // jdirs: 5 joints x 40 verts
    __shared__ float PL[36][65];      // pose transpose staging (+pad)
    const int t = threadIdx.x;

    if (blockIdx.x < GP_J) {
        // ---- Jdirs: 126 slices x 40 verts, Jreg staged in LDS ----
        int slice = blockIdx.x;
        int start = slice * 40;
        int end   = min(start + 40, NV);
        if (t < 200) {
            int j = t / 40, vl = t % 40;
            int v = start + vl;
            JregL[t] = (v < NV) ? Jreg[j * NV + v] : 0.f;
        }
        __syncthreads();
        int s0 = t, s1 = t + 256;
        float a0[5] = {0,0,0,0,0}, a1[5] = {0,0,0,0,0};
        #pragma unroll 2
        for (int v = start; v < end; ++v) {
            int vl = v - start;
            float x0 = (s0 < 450) ? sdirs[(size_t)v * 450 + s0]
                     : (s0 < 453 ? vt[v * 3 + (s0 - 450)] : 0.f);
            float x1 = (s1 < 450) ? sdirs[(size_t)v * 450 + s1]
                     : (s1 < 453 ? vt[v * 3 + (s1 - 450)] : 0.f);
            #pragma unroll
            for (int j = 0; j < 5; ++j) {
                float w = JregL[j * 40 + vl];
                a0[j] += w * x0; a1[j] += w * x1;
            }
        }
        float* Jd = (float*)(ws + WS_JD_B);
        #pragma unroll
        for (int j = 0; j < 5; ++j) {
            if (s0 < 453) atomicAdd(&Jd[j * 453 + s0], a0[j]);
            if (s1 < 453) atomicAdd(&Jd[j * 453 + s1], a1[j]);
        }
    } else if (blockIdx.x < GP_J + GP_S) {
        // ---- B cols 0..143: branch-free, aligned float2 reads, int4 writes ----
        int idx = (blockIdx.x - GP_J) * 256 + t;
        if (idx < NPAD * 18) {
            int n = idx / 18, g = idx % 18;
            __hip_bfloat16* dst = (__hip_bfloat16*)(ws + WS_BB_B) + (size_t)n * 192 + g * 8;
            if (n < N3) {
                const float* src = sdirs + (size_t)n * 150 + g * 8;   // 8B-aligned
                float2 p0 = *(const float2*)(src);
                float2 p1 = *(const float2*)(src + 2);
                float2 p2 = *(const float2*)(src + 4);
                float2 p3 = *(const float2*)(src + 6);
                unsigned int w[4] = { pk2(p0.x, p0.y), pk2(p1.x, p1.y),
                                      pk2(p2.x, p2.y), pk2(p3.x, p3.y) };
                *(int4*)dst = *(int4*)w;
            } else {
                int4 z = {0, 0, 0, 0};
                *(int4*)dst = z;
            }
        }
    } else {
        // ---- B cols 144..191: pdirs transposed via LDS (coalesced both sides) ----
        int pb = blockIdx.x - (GP_J + GP_S);
        int n0 = pb * 64;
        #pragma unroll
        for (int j = 0; j < 9; ++j) {
            int flat = j * 256 + t;          // < 2304 = 36*64
            int k = flat >> 6, i = flat & 63;
            int n = n0 + i;
            PL[k][i] = (n < N3) ? pdirs[(size_t)k * N3 + n] : 0.f;
        }
        __syncthreads();
        #pragma unroll
        for (int j = 0; j < 2; ++j) {
            int idx2 = j * 256 + t;
            if (idx2 < 384) {                // 64 rows x 6 int4
                int r = idx2 / 6, g = idx2 % 6;
                int n = n0 + r;
                int k0 = 144 + g * 8;
                __hip_bfloat16 val[8];
                #pragma unroll
                for (int e = 0; e < 8; ++e) {
                    int k = k0 + e;
                    float v = 0.f;
                    if (k < 150)      v = (n < N3) ? sdirs[(size_t)n * 150 + k] : 0.f;
                    else if (k < 186) v = PL[k - 150][r];
                    val[e] = __float2bfloat16(v);
                }
                *(int4*)((__hip_bfloat16*)(ws + WS_BB_B) + (size_t)n * 192 + k0) = *(int4*)val;
            }
        }
    }
}

// ---------------- rodrigues helper (inlined, static indexing) ----------------
static __device__ __forceinline__ void rodr3(float rx, float ry, float rz, float* R) {
    float ax = rx + 1e-8f, ay = ry + 1e-8f, az = rz + 1e-8f;
    float angle = sqrtf(ax*ax + ay*ay + az*az);
    float inv = 1.f / angle;
    float ux = rx * inv, uy = ry * inv, uz = rz * inv;
    float c = cosf(angle), s = sinf(angle);
    float K[9] = {0.f, -uz, uy,  uz, 0.f, -ux,  -uy, ux, 0.f};
    float KK[9];
    #pragma unroll
    for (int r = 0; r < 3; ++r)
        #pragma unroll
        for (int cc = 0; cc < 3; ++cc) {
            float a = 0.f;
            #pragma unroll
            for (int m = 0; m < 3; ++m) a += K[r*3+m] * K[m*3+cc];
            KK[r*3+cc] = a;
        }
    #pragma unroll
    for (int e = 0; e < 9; ++e) R[e] = s * K[e] + (1.f - c) * KK[e];
    R[0] += 1.f; R[4] += 1.f; R[8] += 1.f;
}

// ---------------- per-batch: coalesced LDS-staged version ----------------
#define KBS 0        // shp staged [64][101]
#define KBE 6464     // exp staged [64][51]
#define KBJ 9728     // Jd [2265]
#define KBR 11993    // reduction [4][64][17]
#define KBP 16345    // pf [64][37]
#define KBT 18713    // total floats (74852 B)

__global__ __launch_bounds__(256) void k_batch(
        const float* __restrict__ shp,
        const float* __restrict__ expn,
        const float* __restrict__ neck,
        const float* __restrict__ jaw,
        const float* __restrict__ eye,
        char* __restrict__ ws) {
    __shared__ float L[KBT];
    const int t  = threadIdx.x;
    const int b0 = blockIdx.x * 64;

    {
        const float* Jd = (const float*)(ws + WS_JD_B);
        for (int i = t; i < 6400; i += 256) { int r = i / 100, c = i - r * 100; L[KBS + r*101 + c] = shp[(size_t)b0*100 + i]; }
        for (int i = t; i < 3200; i += 256) { int r = i / 50,  c = i - r * 50;  L[KBE + r*51  + c] = expn[(size_t)b0*50 + i]; }
        for (int i = t; i < 2265; i += 256) L[KBJ + i] = Jd[i];
    }
    __syncthreads();

    const int br = t & 63, seg = t >> 6;   // seg uniform per wave
    {
        float Jp[15];
        #pragma unroll
        for (int u = 0; u < 15; ++u) Jp[u] = 0.f;
        int l0 = seg * 38, l1 = (seg == 3) ? 150 : (l0 + 38);
        for (int l = l0; l < l1; ++l) {
            float be = (l < 100) ? L[KBS + br*101 + l] : L[KBE + br*51 + (l - 100)];
            #pragma unroll
            for (int jj = 0; jj < 5; ++jj)
                #pragma unroll
                for (int kk = 0; kk < 3; ++kk)
                    Jp[jj*3 + kk] += L[KBJ + jj*453 + kk*150 + l] * be;
        }
        #pragma unroll
        for (int u = 0; u < 15; ++u) L[KBR + (seg*64 + br)*17 + u] = Jp[u];
    }
    __syncthreads();

    if (t < 64) {
        int b = b0 + t;
        float J[15];
        #pragma unroll
        for (int jk = 0; jk < 15; ++jk) {
            float s = L[KBJ + (jk/3)*453 + 450 + (jk%3)];
            #pragma unroll
            for (int sg = 0; sg < 4; ++sg) s += L[KBR + (sg*64 + t)*17 + jk];
            J[jk] = s;
        }

        float R[4][9];
        rodr3(neck[b*3], neck[b*3+1], neck[b*3+2], R[0]);
        rodr3(jaw[b*3],  jaw[b*3+1],  jaw[b*3+2],  R[1]);
        rodr3(eye[b*6],  eye[b*6+1],  eye[b*6+2],  R[2]);
        rodr3(eye[b*6+3], eye[b*6+4], eye[b*6+5],  R[3]);

        // pf = R - I -> LDS for the A-write phase
        #pragma unroll
        for (int kk2 = 0; kk2 < 4; ++kk2)
            #pragma unroll
            for (int e = 0; e < 9; ++e)
                L[KBP + t*37 + kk2*9 + e] = R[kk2][e] - ((e == 0 || e == 4 || e == 8) ? 1.f : 0.f);

        // chain -> Atr (joint0 = I; G1 = [R1|J1]; Gk = [R1*Rk | R1*(Jk-J1)+J1])
        float* Atr = (float*)(ws + WS_ATR_B) + (size_t)b * 60;
        Atr[0]=1.f; Atr[1]=0.f; Atr[2]=0.f;  Atr[3]=0.f;
        Atr[4]=0.f; Atr[5]=1.f; Atr[6]=0.f;  Atr[7]=0.f;
        Atr[8]=0.f; Atr[9]=0.f; Atr[10]=1.f; Atr[11]=0.f;
        #pragma unroll
        for (int r = 0; r < 3; ++r) {
            float d = R[0][r*3+0]*J[3] + R[0][r*3+1]*J[4] + R[0][r*3+2]*J[5];
            Atr[12 + r*4 + 0] = R[0][r*3+0];
            Atr[12 + r*4 + 1] = R[0][r*3+1];
            Atr[12 + r*4 + 2] = R[0][r*3+2];
            Atr[12 + r*4 + 3] = J[3+r] - d;
        }
        #pragma unroll
        for (int kk = 1; kk < 4; ++kk) {
            int jj = kk + 1;
            float rel[3];
            #pragma unroll
            for (int r = 0; r < 3; ++r) rel[r] = J[jj*3+r] - J[3+r];
            float Gr[9], tv[3];
            #pragma unroll
            for (int r = 0; r < 3; ++r) {
                #pragma unroll
                for (int cc = 0; cc < 3; ++cc) {
                    float a = 0.f;
                    #pragma unroll
                    for (int m = 0; m < 3; ++m) a += R[0][r*3+m] * R[kk][m*3+cc];
                    Gr[r*3+cc] = a;
                }
                tv[r] = R[0][r*3+0]*rel[0] + R[0][r*3+1]*rel[1] + R[0][r*3+2]*rel[2] + J[3+r];
            }
            #pragma unroll
            for (int r = 0; r < 3; ++r) {
                float d = Gr[r*3+0]*J[jj*3+0] + Gr[r*3+1]*J[jj*3+1] + Gr[r*3+2]*J[jj*3+2];
                Atr[jj*12 + r*4 + 0] = Gr[r*3+0];
                Atr[jj*12 + r*4 + 1] = Gr[r*3+1];
                Atr[jj*12 + r*4 + 2] = Gr[r*3+2];
                Atr[jj*12 + r*4 + 3] = tv[r] - d;
            }
        }
    }
    __syncthreads();

    // bf16 A rows [64][96 words], coalesced
    unsigned int* A32g = (unsigned int*)(ws + WS_AB_B);
    for (int i = t; i < 6144; i += 256) {
        int r = i / 96, w = i - r * 96;
        unsigned int val;
        if (w < 50)      val = pk2(L[KBS + r*101 + 2*w],     L[KBS + r*101 + 2*w + 1]);
        else if (w < 75) { int c = 2*(w-50); val = pk2(L[KBE + r*51 + c], L[KBE + r*51 + c + 1]); }
        else if (w < 93) { int c = 2*(w-75); val = pk2(L[KBP + r*37 + c], L[KBP + r*37 + c + 1]); }
        else             val = 0u;
        A32g[(size_t)(b0 + r)*96 + w] = val;
    }
}

// ---------------- mega: bf16 MFMA GEMM + fused LBS epilogue ----------------
// M=32 batch x N=192 cols per block, K=192 (3 chunks of 64). 4 waves.
// Epilogue restructured register-lean: lane = vertex (64 verts), wave = 4-row
// group. Atr row address is wave-uniform -> direct global float4 reads
// (L2-hot, scalarizable), r-sliced to a 20-float working set. No ar[60],
// no atrS LDS staging -> peak epilogue regs ~35, enabling (256,5):
// 5 blocks/CU = 20 waves = 62.5% occupancy (R6's spill tell was VGPR=48 +
// WRITE>200MB; with the lean epilogue the 96-reg budget should hold).
#define A_OFF  0          // 32 * 136 = 4352
#define B_OFF  4352       // 192 * 136 = 26112 -> 30464
#define S_VT   17         // vtT word stride (17 odd -> 2 lanes/bank, free)
#define VT_T_OFF 0        // 192*17*4 = 13056
#define VTQ_OFF  13056    // 192*4 = 768 -> 13824
#define LBS_OFF  13824    // 320*4 = 1280 -> 15104
#define SMEM_BYTES 30464  // GEMM stage dominates

__global__ __launch_bounds__(256, 5) void k_mega(
        const char* __restrict__ ws,
        const float* __restrict__ vt,     // [N3]
        const float* __restrict__ lbsw,   // [NV][5]
        float* __restrict__ out) {
    __shared__ __align__(16) unsigned char smem[SMEM_BYTES];
    const unsigned char* AbG = (const unsigned char*)ws + WS_AB_B;
    const unsigned char* BbG = (const unsigned char*)ws + WS_BB_B;
    const float* AtrG = (const float*)(ws + WS_ATR_B);

    const int ntile = blockIdx.y;          // 0..78
    const int b0    = blockIdx.x * 32;     // 64 tiles
    const int t     = threadIdx.x;
    const int lane  = t & 63;
    const int wn    = t >> 6;              // wave id
    const int l15 = lane & 15, quad = lane >> 4;

    floatx4 acc[2][3];
    #pragma unroll
    for (int f = 0; f < 2; ++f)
        #pragma unroll
        for (int g = 0; g < 3; ++g) {
            floatx4 z = {0.f, 0.f, 0.f, 0.f};
            acc[f][g] = z;
        }

    for (int chunk = 0; chunk < 3; ++chunk) {
        __syncthreads();
        // A: 32 rows x 128 B (one float4 per thread)
        {
            int row = t >> 3, piece = t & 7;
            *(float4*)(smem + A_OFF + row * 136 + piece * 16) =
                *(const float4*)(AbG + (size_t)(b0 + row) * 384 + chunk * 128 + piece * 16);
        }
        // B: 192 rows x 128 B
        #pragma unroll
        for (int i = 0; i < 6; ++i) {
            int flat = i * 256 + t;
            int row = flat >> 3, piece = flat & 7;
            *(float4*)(smem + B_OFF + row * 136 + piece * 16) =
                *(const float4*)(BbG + (size_t)(ntile * 192 + row) * 384 + chunk * 128 + piece * 16);
        }
        __syncthreads();
        #pragma unroll
        for (int ks = 0; ks < 2; ++ks) {
            short8 af[2];
            #pragma unroll
            for (int f = 0; f < 2; ++f)
                af[f] = *(const short8*)(smem + A_OFF + (f * 16 + l15) * 136 + ks * 64 + quad * 16);
            #pragma unroll
            for (int g = 0; g < 3; ++g) {
                short8 bf = *(const short8*)(smem + B_OFF + (wn * 48 + g * 16 + l15) * 136 + ks * 64 + quad * 16);
                #pragma unroll
                for (int f = 0; f < 2; ++f)
                    acc[f][g] = __builtin_amdgcn_mfma_f32_16x16x32_bf16(af[f], bf, acc[f][g], 0, 0, 0);
            }
        }
    }
    __syncthreads();

    float* vtT  = (float*)(smem + VT_T_OFF);   // [192 cols][17]
    float* vtQ  = (float*)(smem + VTQ_OFF);    // [192]
    float* lbsS = (float*)(smem + LBS_OFF);    // [64][5]

    // stage per-vertex constants once
    if (t < 192) { int n = ntile * 192 + t; vtQ[t] = (n < N3) ? vt[n] : 0.f; }
    for (int i = t; i < 320; i += 256) {
        int v = ntile * 64 + i / 5;
        lbsS[i] = (v < NV) ? lbsw[(size_t)v * 5 + (i % 5)] : 0.f;
    }
    BAR_LGKM();

    // per-lane vertex constants (lane = vert), held across both halves
    float wj0 = lbsS[lane*5+0], wj1 = lbsS[lane*5+1], wj2 = lbsS[lane*5+2],
          wj3 = lbsS[lane*5+3], wj4 = lbsS[lane*5+4];
    float vq0 = vtQ[lane*3+0], vq1 = vtQ[lane*3+1], vq2 = vtQ[lane*3+2];

    #pragma unroll
    for (int HH = 0; HH < 2; ++HH) {
        if (HH) BAR_LGKM();   // store phase of half 0 done reading vtT
        // dump acc[HH] rows 0..15 -> vtT[col][rl]
        #pragma unroll
        for (int g = 0; g < 3; ++g) {
            int col = wn * 48 + g * 16 + l15;
            int rl  = quad * 4;
            #pragma unroll
            for (int r = 0; r < 4; ++r)
                vtT[col * S_VT + rl + r] = acc[HH][g][r];
        }
        BAR_LGKM();

        // LBS: wave wn handles rows wn*4 .. wn*4+3; lane = vertex
        #pragma unroll
        for (int i = 0; i < 4; ++i) {
            int row = wn * 4 + i;
            int rowg = __builtin_amdgcn_readfirstlane(b0 + HH * 16 + row);
            const float* ar = AtrG + (size_t)rowg * 60;
            float px = vtT[(lane*3+0) * S_VT + row] + vq0;
            float py = vtT[(lane*3+1) * S_VT + row] + vq1;
            float pz = vtT[(lane*3+2) * S_VT + row] + vq2;
            float y[3];
            #pragma unroll
            for (int r = 0; r < 3; ++r) {
                float4 a0 = *(const float4*)(ar +  0 + r*4);
                float4 a1 = *(const float4*)(ar + 12 + r*4);
                float4 a2 = *(const float4*)(ar + 24 + r*4);
                float4 a3 = *(const float4*)(ar + 36 + r*4);
                float4 a4 = *(const float4*)(ar + 48 + r*4);
                float t0 = wj0*a0.x + wj1*a1.x + wj2*a2.x + wj3*a3.x + wj4*a4.x;
                float t1 = wj0*a0.y + wj1*a1.y + wj2*a2.y + wj3*a3.y + wj4*a4.y;
                float t2 = wj0*a0.z + wj1*a1.z + wj2*a2.z + wj3*a3.z + wj4*a4.z;
                float t3 = wj0*a0.w + wj1*a1.w + wj2*a2.w + wj3*a3.w + wj4*a4.w;
                y[r] = t0*px + t1*py + t2*pz + t3;
            }
            vtT[(lane*3+0) * S_VT + row] = y[0];
            vtT[(lane*3+1) * S_VT + row] = y[1];
            vtT[(lane*3+2) * S_VT + row] = y[2];
        }
        BAR_LGKM();

        // transpose out: per row, 3 coalesced dword stores of 64 cols each
        {
            const bool full = (ntile * 192 + 192 <= N3);
            for (int rr = wn; rr < 16; rr += 4) {
                size_t ob = (size_t)(b0 + HH * 16 + rr) * N3 + (size_t)ntile * 192;
                if (full) {
                    #pragma unroll
                    for (int e = 0; e < 3; ++e) {
                        int col = e * 64 + lane;
                        out[ob + col] = vtT[col * S_VT + rr];
                    }
                } else {
                    #pragma unroll
                    for (int e = 0; e < 3; ++e) {
                        int col = e * 64 + lane;
                        if (ntile * 192 + col < N3)
                            out[ob + col] = vtT[col * S_VT + rr];
                    }
                }
            }
        }
    }
}

extern "C" void kernel_launch(void* const* d_in, const int* in_sizes, int n_in,
                              void* d_out, int out_size, void* d_ws, size_t ws_size,
                              hipStream_t stream) {
    const float* shp  = (const float*)d_in[0];
    const float* expn = (const float*)d_in[1];
    const float* neck = (const float*)d_in[2];
    const float* jaw  = (const float*)d_in[3];
    const float* eye  = (const float*)d_in[4];
    const float* vt   = (const float*)d_in[5];
    const float* sdir = (const float*)d_in[6];
    const float* pdir = (const float*)d_in[7];
    const float* jreg = (const float*)d_in[8];
    const float* lbsw = (const float*)d_in[9];
    char* ws  = (char*)d_ws;
    float* out = (float*)d_out;

    hipMemsetAsync(ws + WS_JD_B, 0, 2272 * 4, stream);
    k_prep <<<GP_J + GP_S + GP_P, 256, 0, stream>>>(jreg, sdir, vt, pdir, ws);
    k_batch<<<32, 256, 0, stream>>>(shp, expn, neck, jaw, eye, ws);
    k_mega <<<dim3(64, NTIL), 256, 0, stream>>>(ws, vt, lbsw, out);
}

// Round 9
// 257.152 us; speedup vs baseline: 1.1372x; 1.1372x over previous
//
#include <hip/hip_runtime.h>
#include <hip/hip_bf16.h>
#include <math.h>

#define NV   5023
#define N3   15069
#define NB   2048
#define NTIL 79            // ceil(N3/192) column tiles
#define NPAD (NTIL*192)    // 15168 padded B rows

// ---- workspace byte offsets ----
#define WS_JD_B   0          // 2272 floats
#define WS_ATR_B  9216       // 2048*60*4  = 491520
#define WS_AB_B   795648     // 2048*192*2 = 786432 (bf16 A)
#define WS_BB_B   1582080    // 15168*192*2 = 5824512 (bf16 B, n-major, padded)

// k_prep block ranges
#define GP_J 126             // jdirs slices
#define GP_S 1067            // sdirs->B cols 0..143 (NPAD*18 int4 / 256)
#define GP_P 237             // pose cols 144..191 (NPAD/64)

typedef __attribute__((ext_vector_type(8))) short short8;
typedef __attribute__((ext_vector_type(4))) float floatx4;

static __device__ __forceinline__ unsigned short f2bf(float x) {
    union { __hip_bfloat16 h; unsigned short s; } u;
    u.h = __float2bfloat16(x);
    return u.s;
}
static __device__ __forceinline__ unsigned int pk2(float a, float b) {
    return (unsigned int)f2bf(a) | ((unsigned int)f2bf(b) << 16);
}

// lgkmcnt-only barrier: cross-thread LDS ordering without draining the
// vmem queue -- global loads/stores stay in flight across phases.
#define BAR_LGKM() do { \
    asm volatile("s_waitcnt lgkmcnt(0)" ::: "memory"); \
    __builtin_amdgcn_s_barrier(); \
    asm volatile("" ::: "memory"); \
} while (0)

// ---------------- fused prep: jdirs | B cols 0..143 | B cols 144..191 ----------------
__global__ void k_prep(const float* __restrict__ Jreg,   // [5][NV]
                       const float* __restrict__ sdirs,  // [NV][450] == [N3][150]
                       const float* __restrict__ vt,     // [NV][3]
                       const float* __restrict__ pdirs,  // [36][N3]
                       char* __restrict__ ws) {
    __shared__ float JregL[200];      // jdirs: 5 joints x 40 verts
    __shared__ float PL[36][65];      // pose transpose staging (+pad)
    const int t = threadIdx.x;

    if (blockIdx.x < GP_J) {
        // ---- Jdirs: 126 slices x 40 verts, Jreg staged in LDS ----
        int slice = blockIdx.x;
        int start = slice * 40;
        int end   = min(start + 40, NV);
        if (t < 200) {
            int j = t / 40, vl = t % 40;
            int v = start + vl;
            JregL[t] = (v < NV) ? Jreg[j * NV + v] : 0.f;
        }
        __syncthreads();
        int s0 = t, s1 = t + 256;
        float a0[5] = {0,0,0,0,0}, a1[5] = {0,0,0,0,0};
        #pragma unroll 2
        for (int v = start; v < end; ++v) {
            int vl = v - start;
            float x0 = (s0 < 450) ? sdirs[(size_t)v * 450 + s0]
                     : (s0 < 453 ? vt[v * 3 + (s0 - 450)] : 0.f);
            float x1 = (s1 < 450) ? sdirs[(size_t)v * 450 + s1]
                     : (s1 < 453 ? vt[v * 3 + (s1 - 450)] : 0.f);
            #pragma unroll
            for (int j = 0; j < 5; ++j) {
                float w = JregL[j * 40 + vl];
                a0[j] += w * x0; a1[j] += w * x1;
            }
        }
        float* Jd = (float*)(ws + WS_JD_B);
        #pragma unroll
        for (int j = 0; j < 5; ++j) {
            if (s0 < 453) atomicAdd(&Jd[j * 453 + s0], a0[j]);
            if (s1 < 453) atomicAdd(&Jd[j * 453 + s1], a1[j]);
        }
    } else if (blockIdx.x < GP_J + GP_S) {
        // ---- B cols 0..143: branch-free, aligned float2 reads, int4 writes ----
        int idx = (blockIdx.x - GP_J) * 256 + t;
        if (idx < NPAD * 18) {
            int n = idx / 18, g = idx % 18;
            __hip_bfloat16* dst = (__hip_bfloat16*)(ws + WS_BB_B) + (size_t)n * 192 + g * 8;
            if (n < N3) {
                const float* src = sdirs + (size_t)n * 150 + g * 8;   // 8B-aligned
                float2 p0 = *(const float2*)(src);
                float2 p1 = *(const float2*)(src + 2);
                float2 p2 = *(const float2*)(src + 4);
                float2 p3 = *(const float2*)(src + 6);
                unsigned int w[4] = { pk2(p0.x, p0.y), pk2(p1.x, p1.y),
                                      pk2(p2.x, p2.y), pk2(p3.x, p3.y) };
                *(int4*)dst = *(int4*)w;
            } else {
                int4 z = {0, 0, 0, 0};
                *(int4*)dst = z;
            }
        }
    } else {
        // ---- B cols 144..191: pdirs transposed via LDS (coalesced both sides) ----
        int pb = blockIdx.x - (GP_J + GP_S);
        int n0 = pb * 64;
        #pragma unroll
        for (int j = 0; j < 9; ++j) {
            int flat = j * 256 + t;          // < 2304 = 36*64
            int k = flat >> 6, i = flat & 63;
            int n = n0 + i;
            PL[k][i] = (n < N3) ? pdirs[(size_t)k * N3 + n] : 0.f;
        }
        __syncthreads();
        #pragma unroll
        for (int j = 0; j < 2; ++j) {
            int idx2 = j * 256 + t;
            if (idx2 < 384) {                // 64 rows x 6 int4
                int r = idx2 / 6, g = idx2 % 6;
                int n = n0 + r;
                int k0 = 144 + g * 8;
                __hip_bfloat16 val[8];
                #pragma unroll
                for (int e = 0; e < 8; ++e) {
                    int k = k0 + e;
                    float v = 0.f;
                    if (k < 150)      v = (n < N3) ? sdirs[(size_t)n * 150 + k] : 0.f;
                    else if (k < 186) v = PL[k - 150][r];
                    val[e] = __float2bfloat16(v);
                }
                *(int4*)((__hip_bfloat16*)(ws + WS_BB_B) + (size_t)n * 192 + k0) = *(int4*)val;
            }
        }
    }
}

// ---------------- rodrigues helper (inlined, static indexing) ----------------
static __device__ __forceinline__ void rodr3(float rx, float ry, float rz, float* R) {
    float ax = rx + 1e-8f, ay = ry + 1e-8f, az = rz + 1e-8f;
    float angle = sqrtf(ax*ax + ay*ay + az*az);
    float inv = 1.f / angle;
    float ux = rx * inv, uy = ry * inv, uz = rz * inv;
    float c = cosf(angle), s = sinf(angle);
    float K[9] = {0.f, -uz, uy,  uz, 0.f, -ux,  -uy, ux, 0.f};
    float KK[9];
    #pragma unroll
    for (int r = 0; r < 3; ++r)
        #pragma unroll
        for (int cc = 0; cc < 3; ++cc) {
            float a = 0.f;
            #pragma unroll
            for (int m = 0; m < 3; ++m) a += K[r*3+m] * K[m*3+cc];
            KK[r*3+cc] = a;
        }
    #pragma unroll
    for (int e = 0; e < 9; ++e) R[e] = s * K[e] + (1.f - c) * KK[e];
    R[0] += 1.f; R[4] += 1.f; R[8] += 1.f;
}

// ---------------- per-batch: coalesced LDS-staged version ----------------
#define KBS 0        // shp staged [64][101]
#define KBE 6464     // exp staged [64][51]
#define KBJ 9728     // Jd [2265]
#define KBR 11993    // reduction [4][64][17]
#define KBP 16345    // pf [64][37]
#define KBT 18713    // total floats (74852 B)

__global__ __launch_bounds__(256) void k_batch(
        const float* __restrict__ shp,
        const float* __restrict__ expn,
        const float* __restrict__ neck,
        const float* __restrict__ jaw,
        const float* __restrict__ eye,
        char* __restrict__ ws) {
    __shared__ float L[KBT];
    const int t  = threadIdx.x;
    const int b0 = blockIdx.x * 64;

    {
        const float* Jd = (const float*)(ws + WS_JD_B);
        for (int i = t; i < 6400; i += 256) { int r = i / 100, c = i - r * 100; L[KBS + r*101 + c] = shp[(size_t)b0*100 + i]; }
        for (int i = t; i < 3200; i += 256) { int r = i / 50,  c = i - r * 50;  L[KBE + r*51  + c] = expn[(size_t)b0*50 + i]; }
        for (int i = t; i < 2265; i += 256) L[KBJ + i] = Jd[i];
    }
    __syncthreads();

    const int br = t & 63, seg = t >> 6;   // seg uniform per wave
    {
        float Jp[15];
        #pragma unroll
        for (int u = 0; u < 15; ++u) Jp[u] = 0.f;
        int l0 = seg * 38, l1 = (seg == 3) ? 150 : (l0 + 38);
        for (int l = l0; l < l1; ++l) {
            float be = (l < 100) ? L[KBS + br*101 + l] : L[KBE + br*51 + (l - 100)];
            #pragma unroll
            for (int jj = 0; jj < 5; ++jj)
                #pragma unroll
                for (int kk = 0; kk < 3; ++kk)
                    Jp[jj*3 + kk] += L[KBJ + jj*453 + kk*150 + l] * be;
        }
        #pragma unroll
        for (int u = 0; u < 15; ++u) L[KBR + (seg*64 + br)*17 + u] = Jp[u];
    }
    __syncthreads();

    if (t < 64) {
        int b = b0 + t;
        float J[15];
        #pragma unroll
        for (int jk = 0; jk < 15; ++jk) {
            float s = L[KBJ + (jk/3)*453 + 450 + (jk%3)];
            #pragma unroll
            for (int sg = 0; sg < 4; ++sg) s += L[KBR + (sg*64 + t)*17 + jk];
            J[jk] = s;
        }

        float R[4][9];
        rodr3(neck[b*3], neck[b*3+1], neck[b*3+2], R[0]);
        rodr3(jaw[b*3],  jaw[b*3+1],  jaw[b*3+2],  R[1]);
        rodr3(eye[b*6],  eye[b*6+1],  eye[b*6+2],  R[2]);
        rodr3(eye[b*6+3], eye[b*6+4], eye[b*6+5],  R[3]);

        // pf = R - I -> LDS for the A-write phase
        #pragma unroll
        for (int kk2 = 0; kk2 < 4; ++kk2)
            #pragma unroll
            for (int e = 0; e < 9; ++e)
                L[KBP + t*37 + kk2*9 + e] = R[kk2][e] - ((e == 0 || e == 4 || e == 8) ? 1.f : 0.f);

        // chain -> Atr (joint0 = I; G1 = [R1|J1]; Gk = [R1*Rk | R1*(Jk-J1)+J1])
        float* Atr = (float*)(ws + WS_ATR_B) + (size_t)b * 60;
        Atr[0]=1.f; Atr[1]=0.f; Atr[2]=0.f;  Atr[3]=0.f;
        Atr[4]=0.f; Atr[5]=1.f; Atr[6]=0.f;  Atr[7]=0.f;
        Atr[8]=0.f; Atr[9]=0.f; Atr[10]=1.f; Atr[11]=0.f;
        #pragma unroll
        for (int r = 0; r < 3; ++r) {
            float d = R[0][r*3+0]*J[3] + R[0][r*3+1]*J[4] + R[0][r*3+2]*J[5];
            Atr[12 + r*4 + 0] = R[0][r*3+0];
            Atr[12 + r*4 + 1] = R[0][r*3+1];
            Atr[12 + r*4 + 2] = R[0][r*3+2];
            Atr[12 + r*4 + 3] = J[3+r] - d;
        }
        #pragma unroll
        for (int kk = 1; kk < 4; ++kk) {
            int jj = kk + 1;
            float rel[3];
            #pragma unroll
            for (int r = 0; r < 3; ++r) rel[r] = J[jj*3+r] - J[3+r];
            float Gr[9], tv[3];
            #pragma unroll
            for (int r = 0; r < 3; ++r) {
                #pragma unroll
                for (int cc = 0; cc < 3; ++cc) {
                    float a = 0.f;
                    #pragma unroll
                    for (int m = 0; m < 3; ++m) a += R[0][r*3+m] * R[kk][m*3+cc];
                    Gr[r*3+cc] = a;
                }
                tv[r] = R[0][r*3+0]*rel[0] + R[0][r*3+1]*rel[1] + R[0][r*3+2]*rel[2] + J[3+r];
            }
            #pragma unroll
            for (int r = 0; r < 3; ++r) {
                float d = Gr[r*3+0]*J[jj*3+0] + Gr[r*3+1]*J[jj*3+1] + Gr[r*3+2]*J[jj*3+2];
                Atr[jj*12 + r*4 + 0] = Gr[r*3+0];
                Atr[jj*12 + r*4 + 1] = Gr[r*3+1];
                Atr[jj*12 + r*4 + 2] = Gr[r*3+2];
                Atr[jj*12 + r*4 + 3] = tv[r] - d;
            }
        }
    }
    __syncthreads();

    // bf16 A rows [64][96 words], coalesced
    unsigned int* A32g = (unsigned int*)(ws + WS_AB_B);
    for (int i = t; i < 6144; i += 256) {
        int r = i / 96, w = i - r * 96;
        unsigned int val;
        if (w < 50)      val = pk2(L[KBS + r*101 + 2*w],     L[KBS + r*101 + 2*w + 1]);
        else if (w < 75) { int c = 2*(w-50); val = pk2(L[KBE + r*51 + c], L[KBE + r*51 + c + 1]); }
        else if (w < 93) { int c = 2*(w-75); val = pk2(L[KBP + r*37 + c], L[KBP + r*37 + c + 1]); }
        else             val = 0u;
        A32g[(size_t)(b0 + r)*96 + w] = val;
    }
}

// ---------------- mega: bf16 MFMA GEMM + fused LBS epilogue ----------------
// R7 structure (M=32, (256,4), register-staged Atr epilogue) + T14 pipeline:
// chunk k+1 prefetched into registers during chunk k's MFMA; GEMM barriers are
// lgkmcnt-only so the prefetch loads stay in flight across them (the compiler's
// __syncthreads would drain vmcnt(0) and put L2 latency on the critical path).
// Addressing collapsed to 4 base pointers + immediate offsets (B row i at
// base + i*12288 global / + i*4352 LDS), keeping prefetch regs affordable.
#define A_OFF  0          // 32 * 136 = 4352
#define B_OFF  4352       // 192 * 136 = 26112 -> 30464
#define S_VT   17         // vtT word stride (odd -> conflict-free dword phases)
#define S_AT   61         // atrS word stride (61 coprime 32 -> conflict-free)
#define VT_T_OFF 0        // 192*17*4 = 13056
#define ATR_OFF  13056    // 16*61*4 = 3904 -> 16960
#define VTQ_OFF  16960    // 192*4 = 768 -> 17728
#define LBS_OFF  17728    // 320*4 = 1280 -> 19008
#define SMEM_BYTES 30464

__global__ __launch_bounds__(256, 4) void k_mega(
        const char* __restrict__ ws,
        const float* __restrict__ vt,     // [N3]
        const float* __restrict__ lbsw,   // [NV][5]
        float* __restrict__ out) {
    __shared__ __align__(16) unsigned char smem[SMEM_BYTES];
    const unsigned char* AbG = (const unsigned char*)ws + WS_AB_B;
    const unsigned char* BbG = (const unsigned char*)ws + WS_BB_B;
    const float* AtrG = (const float*)(ws + WS_ATR_B);

    const int ntile = blockIdx.y;          // 0..78
    const int b0    = blockIdx.x * 32;     // 64 tiles
    const int t     = threadIdx.x;
    const int lane  = t & 63;
    const int wn    = t >> 6;              // wave id
    const int l15 = lane & 15, quad = lane >> 4;

    floatx4 acc[2][3];
    #pragma unroll
    for (int f = 0; f < 2; ++f)
        #pragma unroll
        for (int g = 0; g < 3; ++g) {
            floatx4 z = {0.f, 0.f, 0.f, 0.f};
            acc[f][g] = z;
        }

    // hoisted epilogue preload: half-0 Atr (independent of GEMM) issues early,
    // latency hidden under the whole GEMM phase
    float arA[4], arB[4];
    #pragma unroll
    for (int u = 0; u < 4; ++u) {
        int i = u * 256 + t;
        arA[u] = (i < 960) ? AtrG[(size_t)b0 * 60 + i] : 0.f;
    }

    // staging bases (row = t>>3, piece = t&7); B row i = base + i*12288 (global)
    // / + i*4352 (LDS); chunk c = +c*128 (global)
    const unsigned char* aSrc = AbG + (size_t)(b0 + (t >> 3)) * 384 + (t & 7) * 16;
    const unsigned char* bSrc = BbG + (size_t)(ntile * 192 + (t >> 3)) * 384 + (t & 7) * 16;
    unsigned char* aDst = smem + A_OFF + (t >> 3) * 136 + (t & 7) * 16;
    unsigned char* bDst = smem + B_OFF + (t >> 3) * 136 + (t & 7) * 16;

    // prefetch chunk 0
    float4 pa  = *(const float4*)(aSrc);
    float4 pb0 = *(const float4*)(bSrc);
    float4 pb1 = *(const float4*)(bSrc + 12288);
    float4 pb2 = *(const float4*)(bSrc + 24576);
    float4 pb3 = *(const float4*)(bSrc + 36864);
    float4 pb4 = *(const float4*)(bSrc + 49152);
    float4 pb5 = *(const float4*)(bSrc + 61440);

    #pragma unroll
    for (int chunk = 0; chunk < 3; ++chunk) {
        BAR_LGKM();   // all waves done reading LDS from previous chunk
        // regs -> LDS (ds_write auto-waits on each load's vmcnt)
        *(float4*)(aDst)         = pa;
        *(float4*)(bDst)         = pb0;
        *(float4*)(bDst +  4352) = pb1;
        *(float4*)(bDst +  8704) = pb2;
        *(float4*)(bDst + 13056) = pb3;
        *(float4*)(bDst + 17408) = pb4;
        *(float4*)(bDst + 21760) = pb5;
        // issue next-chunk loads; they stay in flight through MFMA + barriers
        if (chunk < 2) {
            pa  = *(const float4*)(aSrc + (chunk + 1) * 128);
            pb0 = *(const float4*)(bSrc + (chunk + 1) * 128);
            pb1 = *(const float4*)(bSrc + 12288 + (chunk + 1) * 128);
            pb2 = *(const float4*)(bSrc + 24576 + (chunk + 1) * 128);
            pb3 = *(const float4*)(bSrc + 36864 + (chunk + 1) * 128);
            pb4 = *(const float4*)(bSrc + 49152 + (chunk + 1) * 128);
            pb5 = *(const float4*)(bSrc + 61440 + (chunk + 1) * 128);
        }
        BAR_LGKM();   // LDS writes visible to all waves
        #pragma unroll
        for (int ks = 0; ks < 2; ++ks) {
            short8 af[2];
            #pragma unroll
            for (int f = 0; f < 2; ++f)
                af[f] = *(const short8*)(smem + A_OFF + (f * 16 + l15) * 136 + ks * 64 + quad * 16);
            #pragma unroll
            for (int g = 0; g < 3; ++g) {
                short8 bf = *(const short8*)(smem + B_OFF + (wn * 48 + g * 16 + l15) * 136 + ks * 64 + quad * 16);
                #pragma unroll
                for (int f = 0; f < 2; ++f)
                    acc[f][g] = __builtin_amdgcn_mfma_f32_16x16x32_bf16(af[f], bf, acc[f][g], 0, 0, 0);
            }
        }
    }
    BAR_LGKM();   // MFMA ds_reads drained before epilogue regions overwrite A/B

    float* vtT  = (float*)(smem + VT_T_OFF);   // [192 cols][17]
    float* atrS = (float*)(smem + ATR_OFF);    // [16][61]
    float* vtQ  = (float*)(smem + VTQ_OFF);    // [192]
    float* lbsS = (float*)(smem + LBS_OFF);    // [64][5]

    // stage per-vertex constants once (ordered by the next BAR_LGKM)
    if (t < 192) { int n = ntile * 192 + t; vtQ[t] = (n < N3) ? vt[n] : 0.f; }
    for (int i = t; i < 320; i += 256) {
        int v = ntile * 64 + i / 5;
        lbsS[i] = (v < NV) ? lbsw[(size_t)v * 5 + (i % 5)] : 0.f;
    }

    // H = 0 and H = 1 written via macro so all reg-array indexing is static
    #define EPI_PHASE(HH, ARCUR, PRELOAD_NEXT)                                          \
    {                                                                                   \
        BAR_LGKM();                                                                     \
        /* dump acc rows [HH*16, HH*16+16) -> vtT[col][rl] */                           \
        _Pragma("unroll")                                                               \
        for (int g = 0; g < 3; ++g) {                                                   \
            int col = wn * 48 + g * 16 + l15;                                           \
            int rl  = quad * 4;                                                         \
            _Pragma("unroll")                                                           \
            for (int r = 0; r < 4; ++r)                                                 \
                vtT[col * S_VT + rl + r] = acc[HH][g][r];                               \
        }                                                                               \
        /* Atr -> LDS from registers */                                                 \
        _Pragma("unroll")                                                               \
        for (int u = 0; u < 4; ++u) {                                                   \
            int i = u * 256 + t;                                                        \
            if (i < 960) {                                                              \
                int rw = i / 60, cw = i - rw * 60;                                      \
                atrS[rw * S_AT + cw] = ARCUR[u];                                        \
            }                                                                           \
        }                                                                               \
        PRELOAD_NEXT                                                                    \
        BAR_LGKM();                                                                     \
        /* LBS: rl = t&15 (row in half), vgrp = t>>4 (4 verts each) */                  \
        {                                                                               \
            int rl = t & 15;                                                            \
            int vgrp = t >> 4;                                                          \
            float ar[60];                                                               \
            _Pragma("unroll")                                                           \
            for (int i = 0; i < 60; ++i) ar[i] = atrS[rl * S_AT + i];                   \
            _Pragma("unroll")                                                           \
            for (int vv = 0; vv < 4; ++vv) {                                            \
                int vloc = vgrp * 4 + vv;                                               \
                int c0 = vloc * 3;                                                      \
                float w0 = lbsS[vloc*5+0], w1 = lbsS[vloc*5+1], w2 = lbsS[vloc*5+2],    \
                      w3 = lbsS[vloc*5+3], w4 = lbsS[vloc*5+4];                         \
                float px = vtT[(c0+0) * S_VT + rl] + vtQ[c0+0];                         \
                float py = vtT[(c0+1) * S_VT + rl] + vtQ[c0+1];                         \
                float pz = vtT[(c0+2) * S_VT + rl] + vtQ[c0+2];                         \
                float y[3];                                                             \
                _Pragma("unroll")                                                       \
                for (int r = 0; r < 3; ++r) {                                           \
                    float t0 = w0*ar[ 0+r*4+0] + w1*ar[12+r*4+0] + w2*ar[24+r*4+0]      \
                             + w3*ar[36+r*4+0] + w4*ar[48+r*4+0];                       \
                    float t1 = w0*ar[ 0+r*4+1] + w1*ar[12+r*4+1] + w2*ar[24+r*4+1]      \
                             + w3*ar[36+r*4+1] + w4*ar[48+r*4+1];                       \
                    float t2 = w0*ar[ 0+r*4+2] + w1*ar[12+r*4+2] + w2*ar[24+r*4+2]      \
                             + w3*ar[36+r*4+2] + w4*ar[48+r*4+2];                       \
                    float t3 = w0*ar[ 0+r*4+3] + w1*ar[12+r*4+3] + w2*ar[24+r*4+3]      \
                             + w3*ar[36+r*4+3] + w4*ar[48+r*4+3];                       \
                    y[r] = t0*px + t1*py + t2*pz + t3;                                  \
                }                                                                       \
                vtT[(c0+0) * S_VT + rl] = y[0];                                         \
                vtT[(c0+1) * S_VT + rl] = y[1];                                         \
                vtT[(c0+2) * S_VT + rl] = y[2];                                         \
            }                                                                           \
        }                                                                               \
        BAR_LGKM();                                                                     \
        /* transpose out: per row, 3 coalesced dword stores of 64 cols each */          \
        {                                                                               \
            const bool full = (ntile * 192 + 192 <= N3);                                \
            for (int rr = wn; rr < 16; rr += 4) {                                       \
                size_t ob = (size_t)(b0 + HH * 16 + rr) * N3 + (size_t)ntile * 192;     \
                if (full) {                                                             \
                    _Pragma("unroll")                                                   \
                    for (int e = 0; e < 3; ++e) {                                       \
                        int col = e * 64 + lane;                                        \
                        out[ob + col] = vtT[col * S_VT + rr];                           \
                    }                                                                   \
                } else {                                                                \
                    _Pragma("unroll")                                                   \
                    for (int e = 0; e < 3; ++e) {                                       \
                        int col = e * 64 + lane;                                        \
                        if (ntile * 192 + col < N3)                                     \
                            out[ob + col] = vtT[col * S_VT + rr];                       \
                    }                                                                   \
                }                                                                       \
            }                                                                           \
        }                                                                               \
    }

    EPI_PHASE(0, arA,
        { _Pragma("unroll")
          for (int u = 0; u < 4; ++u) {
              int i = u * 256 + t;
              arB[u] = (i < 960) ? AtrG[(size_t)(b0 + 16) * 60 + i] : 0.f;
          } } )
    EPI_PHASE(1, arB, { } )
    #undef EPI_PHASE
}

extern "C" void kernel_launch(void* const* d_in, const int* in_sizes, int n_in,
                              void* d_out, int out_size, void* d_ws, size_t ws_size,
                              hipStream_t stream) {
    const float* shp  = (const float*)d_in[0];
    const float* expn = (const float*)d_in[1];
    const float* neck = (const float*)d_in[2];
    const float* jaw  = (const float*)d_in[3];
    const float* eye  = (const float*)d_in[4];
    const float* vt   = (const float*)d_in[5];
    const float* sdir = (const float*)d_in[6];
    const float* pdir = (const float*)d_in[7];
    const float* jreg = (const float*)d_in[8];
    const float* lbsw = (const float*)d_in[9];
    char* ws  = (char*)d_ws;
    float* out = (float*)d_out;

    hipMemsetAsync(ws + WS_JD_B, 0, 2272 * 4, stream);
    k_prep <<<GP_J + GP_S + GP_P, 256, 0, stream>>>(jreg, sdir, vt, pdir, ws);
    k_batch<<<32, 256, 0, stream>>>(shp, expn, neck, jaw, eye, ws);
    k_mega <<<dim3(64, NTIL), 256, 0, stream>>>(ws, vt, lbsw, out);
}

// Round 10
// 246.708 us; speedup vs baseline: 1.1853x; 1.0423x over previous
//
#include <hip/hip_runtime.h>
#include <hip/hip_bf16.h>
#include <math.h>

#define NV   5023
#define N3   15069
#define NB   2048
#define NTIL 79            // ceil(N3/192) column tiles
#define NPAD (NTIL*192)    // 15168 padded B rows

// ---- workspace byte offsets ----
#define WS_JD_B   0          // 2272 floats
#define WS_ATR_B  9216       // 2048*60*4  = 491520
#define WS_AB_B   795648     // 2048*192*2 = 786432 (bf16 A)
#define WS_BB_B   1582080    // 15168*192*2 = 5824512 (bf16 B, n-major, padded)

// k_prep block ranges
#define GP_J 126             // jdirs slices
#define GP_S 1067            // sdirs->B cols 0..143 (NPAD*18 int4 / 256)
#define GP_P 237             // pose cols 144..191 (NPAD/64)

typedef __attribute__((ext_vector_type(8))) short short8;
typedef __attribute__((ext_vector_type(4))) float floatx4;

static __device__ __forceinline__ unsigned short f2bf(float x) {
    union { __hip_bfloat16 h; unsigned short s; } u;
    u.h = __float2bfloat16(x);
    return u.s;
}
static __device__ __forceinline__ unsigned int pk2(float a, float b) {
    return (unsigned int)f2bf(a) | ((unsigned int)f2bf(b) << 16);
}

// lgkmcnt-only barrier: cross-thread LDS ordering without draining the
// vmem store queue -- stores stay in flight across phases.
#define BAR_LGKM() do { \
    asm volatile("s_waitcnt lgkmcnt(0)" ::: "memory"); \
    __builtin_amdgcn_s_barrier(); \
    asm volatile("" ::: "memory"); \
} while (0)

// ---------------- fused prep: jdirs | B cols 0..143 | B cols 144..191 ----------------
__global__ void k_prep(const float* __restrict__ Jreg,   // [5][NV]
                       const float* __restrict__ sdirs,  // [NV][450] == [N3][150]
                       const float* __restrict__ vt,     // [NV][3]
                       const float* __restrict__ pdirs,  // [36][N3]
                       char* __restrict__ ws) {
    __shared__ float JregL[200];      // jdirs: 5 joints x 40 verts
    __shared__ float PL[36][65];      // pose transpose staging (+pad)
    const int t = threadIdx.x;

    if (blockIdx.x < GP_J) {
        // ---- Jdirs: 126 slices x 40 verts, Jreg staged in LDS ----
        int slice = blockIdx.x;
        int start = slice * 40;
        int end   = min(start + 40, NV);
        if (t < 200) {
            int j = t / 40, vl = t % 40;
            int v = start + vl;
            JregL[t] = (v < NV) ? Jreg[j * NV + v] : 0.f;
        }
        __syncthreads();
        int s0 = t, s1 = t + 256;
        float a0[5] = {0,0,0,0,0}, a1[5] = {0,0,0,0,0};
        #pragma unroll 2
        for (int v = start; v < end; ++v) {
            int vl = v - start;
            float x0 = (s0 < 450) ? sdirs[(size_t)v * 450 + s0]
                     : (s0 < 453 ? vt[v * 3 + (s0 - 450)] : 0.f);
            float x1 = (s1 < 450) ? sdirs[(size_t)v * 450 + s1]
                     : (s1 < 453 ? vt[v * 3 + (s1 - 450)] : 0.f);
            #pragma unroll
            for (int j = 0; j < 5; ++j) {
                float w = JregL[j * 40 + vl];
                a0[j] += w * x0; a1[j] += w * x1;
            }
        }
        float* Jd = (float*)(ws + WS_JD_B);
        #pragma unroll
        for (int j = 0; j < 5; ++j) {
            if (s0 < 453) atomicAdd(&Jd[j * 453 + s0], a0[j]);
            if (s1 < 453) atomicAdd(&Jd[j * 453 + s1], a1[j]);
        }
    } else if (blockIdx.x < GP_J + GP_S) {
        // ---- B cols 0..143: branch-free, aligned float2 reads, int4 writes ----
        int idx = (blockIdx.x - GP_J) * 256 + t;
        if (idx < NPAD * 18) {
            int n = idx / 18, g = idx % 18;
            __hip_bfloat16* dst = (__hip_bfloat16*)(ws + WS_BB_B) + (size_t)n * 192 + g * 8;
            if (n < N3) {
                const float* src = sdirs + (size_t)n * 150 + g * 8;   // 8B-aligned
                float2 p0 = *(const float2*)(src);
                float2 p1 = *(const float2*)(src + 2);
                float2 p2 = *(const float2*)(src + 4);
                float2 p3 = *(const float2*)(src + 6);
                unsigned int w[4] = { pk2(p0.x, p0.y), pk2(p1.x, p1.y),
                                      pk2(p2.x, p2.y), pk2(p3.x, p3.y) };
                *(int4*)dst = *(int4*)w;
            } else {
                int4 z = {0, 0, 0, 0};
                *(int4*)dst = z;
            }
        }
    } else {
        // ---- B cols 144..191: pdirs transposed via LDS (coalesced both sides) ----
        int pb = blockIdx.x - (GP_J + GP_S);
        int n0 = pb * 64;
        #pragma unroll
        for (int j = 0; j < 9; ++j) {
            int flat = j * 256 + t;          // < 2304 = 36*64
            int k = flat >> 6, i = flat & 63;
            int n = n0 + i;
            PL[k][i] = (n < N3) ? pdirs[(size_t)k * N3 + n] : 0.f;
        }
        __syncthreads();
        #pragma unroll
        for (int j = 0; j < 2; ++j) {
            int idx2 = j * 256 + t;
            if (idx2 < 384) {                // 64 rows x 6 int4
                int r = idx2 / 6, g = idx2 % 6;
                int n = n0 + r;
                int k0 = 144 + g * 8;
                __hip_bfloat16 val[8];
                #pragma unroll
                for (int e = 0; e < 8; ++e) {
                    int k = k0 + e;
                    float v = 0.f;
                    if (k < 150)      v = (n < N3) ? sdirs[(size_t)n * 150 + k] : 0.f;
                    else if (k < 186) v = PL[k - 150][r];
                    val[e] = __float2bfloat16(v);
                }
                *(int4*)((__hip_bfloat16*)(ws + WS_BB_B) + (size_t)n * 192 + k0) = *(int4*)val;
            }
        }
    }
}

// ---------------- rodrigues helper (inlined, static indexing) ----------------
static __device__ __forceinline__ void rodr3(float rx, float ry, float rz, float* R) {
    float ax = rx + 1e-8f, ay = ry + 1e-8f, az = rz + 1e-8f;
    float angle = sqrtf(ax*ax + ay*ay + az*az);
    float inv = 1.f / angle;
    float ux = rx * inv, uy = ry * inv, uz = rz * inv;
    float c = cosf(angle), s = sinf(angle);
    float K[9] = {0.f, -uz, uy,  uz, 0.f, -ux,  -uy, ux, 0.f};
    float KK[9];
    #pragma unroll
    for (int r = 0; r < 3; ++r)
        #pragma unroll
        for (int cc = 0; cc < 3; ++cc) {
            float a = 0.f;
            #pragma unroll
            for (int m = 0; m < 3; ++m) a += K[r*3+m] * K[m*3+cc];
            KK[r*3+cc] = a;
        }
    #pragma unroll
    for (int e = 0; e < 9; ++e) R[e] = s * K[e] + (1.f - c) * KK[e];
    R[0] += 1.f; R[4] += 1.f; R[8] += 1.f;
}

// ---------------- per-batch: coalesced LDS-staged version ----------------
#define KBS 0        // shp staged [64][101]
#define KBE 6464     // exp staged [64][51]
#define KBJ 9728     // Jd [2265]
#define KBR 11993    // reduction [4][64][17]
#define KBP 16345    // pf [64][37]
#define KBT 18713    // total floats (74852 B)

__global__ __launch_bounds__(256) void k_batch(
        const float* __restrict__ shp,
        const float* __restrict__ expn,
        const float* __restrict__ neck,
        const float* __restrict__ jaw,
        const float* __restrict__ eye,
        char* __restrict__ ws) {
    __shared__ float L[KBT];
    const int t  = threadIdx.x;
    const int b0 = blockIdx.x * 64;

    {
        const float* Jd = (const float*)(ws + WS_JD_B);
        for (int i = t; i < 6400; i += 256) { int r = i / 100, c = i - r * 100; L[KBS + r*101 + c] = shp[(size_t)b0*100 + i]; }
        for (int i = t; i < 3200; i += 256) { int r = i / 50,  c = i - r * 50;  L[KBE + r*51  + c] = expn[(size_t)b0*50 + i]; }
        for (int i = t; i < 2265; i += 256) L[KBJ + i] = Jd[i];
    }
    __syncthreads();

    const int br = t & 63, seg = t >> 6;   // seg uniform per wave
    {
        float Jp[15];
        #pragma unroll
        for (int u = 0; u < 15; ++u) Jp[u] = 0.f;
        int l0 = seg * 38, l1 = (seg == 3) ? 150 : (l0 + 38);
        for (int l = l0; l < l1; ++l) {
            float be = (l < 100) ? L[KBS + br*101 + l] : L[KBE + br*51 + (l - 100)];
            #pragma unroll
            for (int jj = 0; jj < 5; ++jj)
                #pragma unroll
                for (int kk = 0; kk < 3; ++kk)
                    Jp[jj*3 + kk] += L[KBJ + jj*453 + kk*150 + l] * be;
        }
        #pragma unroll
        for (int u = 0; u < 15; ++u) L[KBR + (seg*64 + br)*17 + u] = Jp[u];
    }
    __syncthreads();

    if (t < 64) {
        int b = b0 + t;
        float J[15];
        #pragma unroll
        for (int jk = 0; jk < 15; ++jk) {
            float s = L[KBJ + (jk/3)*453 + 450 + (jk%3)];
            #pragma unroll
            for (int sg = 0; sg < 4; ++sg) s += L[KBR + (sg*64 + t)*17 + jk];
            J[jk] = s;
        }

        float R[4][9];
        rodr3(neck[b*3], neck[b*3+1], neck[b*3+2], R[0]);
        rodr3(jaw[b*3],  jaw[b*3+1],  jaw[b*3+2],  R[1]);
        rodr3(eye[b*6],  eye[b*6+1],  eye[b*6+2],  R[2]);
        rodr3(eye[b*6+3], eye[b*6+4], eye[b*6+5],  R[3]);

        // pf = R - I -> LDS for the A-write phase
        #pragma unroll
        for (int kk2 = 0; kk2 < 4; ++kk2)
            #pragma unroll
            for (int e = 0; e < 9; ++e)
                L[KBP + t*37 + kk2*9 + e] = R[kk2][e] - ((e == 0 || e == 4 || e == 8) ? 1.f : 0.f);

        // chain -> Atr (joint0 = I; G1 = [R1|J1]; Gk = [R1*Rk | R1*(Jk-J1)+J1])
        float* Atr = (float*)(ws + WS_ATR_B) + (size_t)b * 60;
        Atr[0]=1.f; Atr[1]=0.f; Atr[2]=0.f;  Atr[3]=0.f;
        Atr[4]=0.f; Atr[5]=1.f; Atr[6]=0.f;  Atr[7]=0.f;
        Atr[8]=0.f; Atr[9]=0.f; Atr[10]=1.f; Atr[11]=0.f;
        #pragma unroll
        for (int r = 0; r < 3; ++r) {
            float d = R[0][r*3+0]*J[3] + R[0][r*3+1]*J[4] + R[0][r*3+2]*J[5];
            Atr[12 + r*4 + 0] = R[0][r*3+0];
            Atr[12 + r*4 + 1] = R[0][r*3+1];
            Atr[12 + r*4 + 2] = R[0][r*3+2];
            Atr[12 + r*4 + 3] = J[3+r] - d;
        }
        #pragma unroll
        for (int kk = 1; kk < 4; ++kk) {
            int jj = kk + 1;
            float rel[3];
            #pragma unroll
            for (int r = 0; r < 3; ++r) rel[r] = J[jj*3+r] - J[3+r];
            float Gr[9], tv[3];
            #pragma unroll
            for (int r = 0; r < 3; ++r) {
                #pragma unroll
                for (int cc = 0; cc < 3; ++cc) {
                    float a = 0.f;
                    #pragma unroll
                    for (int m = 0; m < 3; ++m) a += R[0][r*3+m] * R[kk][m*3+cc];
                    Gr[r*3+cc] = a;
                }
                tv[r] = R[0][r*3+0]*rel[0] + R[0][r*3+1]*rel[1] + R[0][r*3+2]*rel[2] + J[3+r];
            }
            #pragma unroll
            for (int r = 0; r < 3; ++r) {
                float d = Gr[r*3+0]*J[jj*3+0] + Gr[r*3+1]*J[jj*3+1] + Gr[r*3+2]*J[jj*3+2];
                Atr[jj*12 + r*4 + 0] = Gr[r*3+0];
                Atr[jj*12 + r*4 + 1] = Gr[r*3+1];
                Atr[jj*12 + r*4 + 2] = Gr[r*3+2];
                Atr[jj*12 + r*4 + 3] = tv[r] - d;
            }
        }
    }
    __syncthreads();

    // bf16 A rows [64][96 words], coalesced
    unsigned int* A32g = (unsigned int*)(ws + WS_AB_B);
    for (int i = t; i < 6144; i += 256) {
        int r = i / 96, w = i - r * 96;
        unsigned int val;
        if (w < 50)      val = pk2(L[KBS + r*101 + 2*w],     L[KBS + r*101 + 2*w + 1]);
        else if (w < 75) { int c = 2*(w-50); val = pk2(L[KBE + r*51 + c], L[KBE + r*51 + c + 1]); }
        else if (w < 93) { int c = 2*(w-75); val = pk2(L[KBP + r*37 + c], L[KBP + r*37 + c + 1]); }
        else             val = 0u;
        A32g[(size_t)(b0 + r)*96 + w] = val;
    }
}

// ---------------- mega: bf16 MFMA GEMM + fused LBS epilogue ----------------
// Best-measured configuration (R7, 247.16 us total): M=32 batch x N=192 cols,
// K=192 (3 chunks of 64), 4 waves, launch_bounds(256,4) -> 128-reg budget fits
// the ~88-96 reg need (acc 24 AGPR + ar[60] epilogue) with NO spill; 4 blocks/CU.
// Grid: x = batch tile (64), y = ntile (79): 5056 blocks -> 4.94 rounds, 94% tail.
// Known walls (measured): (256,5) budget 102 -> spill (+135MB scratch, R6);
// lane=vertex lean epilogue -> redundant VMEM, VALU-bound (R8); T14 prefetch +
// lgkm-only GEMM barriers -> occupancy drop, +10us (R9). This structure is the
// empirical optimum under the harness's ~150us/iter re-poison floor.
#define A_OFF  0          // 32 * 136 = 4352
#define B_OFF  4352       // 192 * 136 = 26112 -> 30464
#define S_VT   17         // vtT word stride (odd -> conflict-free dword phases)
#define S_AT   61         // atrS word stride (61 coprime 32 -> conflict-free)
#define VT_T_OFF 0        // 192*17*4 = 13056
#define ATR_OFF  13056    // 16*61*4 = 3904 -> 16960
#define VTQ_OFF  16960    // 192*4 = 768 -> 17728
#define LBS_OFF  17728    // 320*4 = 1280 -> 19008
#define SMEM_BYTES 30464

__global__ __launch_bounds__(256, 4) void k_mega(
        const char* __restrict__ ws,
        const float* __restrict__ vt,     // [N3]
        const float* __restrict__ lbsw,   // [NV][5]
        float* __restrict__ out) {
    __shared__ __align__(16) unsigned char smem[SMEM_BYTES];
    const unsigned char* AbG = (const unsigned char*)ws + WS_AB_B;
    const unsigned char* BbG = (const unsigned char*)ws + WS_BB_B;
    const float* AtrG = (const float*)(ws + WS_ATR_B);

    const int ntile = blockIdx.y;          // 0..78
    const int b0    = blockIdx.x * 32;     // 64 tiles
    const int t     = threadIdx.x;
    const int lane  = t & 63;
    const int wn    = t >> 6;              // wave id
    const int l15 = lane & 15, quad = lane >> 4;

    floatx4 acc[2][3];
    #pragma unroll
    for (int f = 0; f < 2; ++f)
        #pragma unroll
        for (int g = 0; g < 3; ++g) {
            floatx4 z = {0.f, 0.f, 0.f, 0.f};
            acc[f][g] = z;
        }

    for (int chunk = 0; chunk < 3; ++chunk) {
        __syncthreads();
        // A: 32 rows x 128 B (one float4 per thread)
        {
            int row = t >> 3, piece = t & 7;
            *(float4*)(smem + A_OFF + row * 136 + piece * 16) =
                *(const float4*)(AbG + (size_t)(b0 + row) * 384 + chunk * 128 + piece * 16);
        }
        // B: 192 rows x 128 B
        #pragma unroll
        for (int i = 0; i < 6; ++i) {
            int flat = i * 256 + t;
            int row = flat >> 3, piece = flat & 7;
            *(float4*)(smem + B_OFF + row * 136 + piece * 16) =
                *(const float4*)(BbG + (size_t)(ntile * 192 + row) * 384 + chunk * 128 + piece * 16);
        }
        __syncthreads();
        #pragma unroll
        for (int ks = 0; ks < 2; ++ks) {
            short8 af[2];
            #pragma unroll
            for (int f = 0; f < 2; ++f)
                af[f] = *(const short8*)(smem + A_OFF + (f * 16 + l15) * 136 + ks * 64 + quad * 16);
            #pragma unroll
            for (int g = 0; g < 3; ++g) {
                short8 bf = *(const short8*)(smem + B_OFF + (wn * 48 + g * 16 + l15) * 136 + ks * 64 + quad * 16);
                #pragma unroll
                for (int f = 0; f < 2; ++f)
                    acc[f][g] = __builtin_amdgcn_mfma_f32_16x16x32_bf16(af[f], bf, acc[f][g], 0, 0, 0);
            }
        }
    }
    __syncthreads();

    float* vtT  = (float*)(smem + VT_T_OFF);   // [192 cols][17]
    float* atrS = (float*)(smem + ATR_OFF);    // [16][61]
    float* vtQ  = (float*)(smem + VTQ_OFF);    // [192]
    float* lbsS = (float*)(smem + LBS_OFF);    // [64][5]

    // stage per-vertex constants once (ordered by the next BAR_LGKM)
    if (t < 192) { int n = ntile * 192 + t; vtQ[t] = (n < N3) ? vt[n] : 0.f; }
    for (int i = t; i < 320; i += 256) {
        int v = ntile * 64 + i / 5;
        lbsS[i] = (v < NV) ? lbsw[(size_t)v * 5 + (i % 5)] : 0.f;
    }
    // preload half-0 Atr (16 rows x 60 = 960 floats) into registers
    float arA[4], arB[4];
    #pragma unroll
    for (int u = 0; u < 4; ++u) {
        int i = u * 256 + t;
        arA[u] = (i < 960) ? AtrG[(size_t)b0 * 60 + i] : 0.f;
    }

    // H = 0 and H = 1 written via macro so all reg-array indexing is static
    #define EPI_PHASE(HH, ARCUR, PRELOAD_NEXT)                                          \
    {                                                                                   \
        BAR_LGKM();                                                                     \
        /* dump acc rows [HH*16, HH*16+16) -> vtT[col][rl] */                           \
        _Pragma("unroll")                                                               \
        for (int g = 0; g < 3; ++g) {                                                   \
            int col = wn * 48 + g * 16 + l15;                                           \
            int rl  = quad * 4;                                                         \
            _Pragma("unroll")                                                           \
            for (int r = 0; r < 4; ++r)                                                 \
                vtT[col * S_VT + rl + r] = acc[HH][g][r];                               \
        }                                                                               \
        /* Atr -> LDS from registers */                                                 \
        _Pragma("unroll")                                                               \
        for (int u = 0; u < 4; ++u) {                                                   \
            int i = u * 256 + t;                                                        \
            if (i < 960) {                                                              \
                int rw = i / 60, cw = i - rw * 60;                                      \
                atrS[rw * S_AT + cw] = ARCUR[u];                                        \
            }                                                                           \
        }                                                                               \
        PRELOAD_NEXT                                                                    \
        BAR_LGKM();                                                                     \
        /* LBS: rl = t&15 (row in half), vgrp = t>>4 (4 verts each) */                  \
        {                                                                               \
            int rl = t & 15;                                                            \
            int vgrp = t >> 4;                                                          \
            float ar[60];                                                               \
            _Pragma("unroll")                                                           \
            for (int i = 0; i < 60; ++i) ar[i] = atrS[rl * S_AT + i];                   \
            _Pragma("unroll")                                                           \
            for (int vv = 0; vv < 4; ++vv) {                                            \
                int vloc = vgrp * 4 + vv;                                               \
                int c0 = vloc * 3;                                                      \
                float w0 = lbsS[vloc*5+0], w1 = lbsS[vloc*5+1], w2 = lbsS[vloc*5+2],    \
                      w3 = lbsS[vloc*5+3], w4 = lbsS[vloc*5+4];                         \
                float px = vtT[(c0+0) * S_VT + rl] + vtQ[c0+0];                         \
                float py = vtT[(c0+1) * S_VT + rl] + vtQ[c0+1];                         \
                float pz = vtT[(c0+2) * S_VT + rl] + vtQ[c0+2];                         \
                float y[3];                                                             \
                _Pragma("unroll")                                                       \
                for (int r = 0; r < 3; ++r) {                                           \
                    float t0 = w0*ar[ 0+r*4+0] + w1*ar[12+r*4+0] + w2*ar[24+r*4+0]      \
                             + w3*ar[36+r*4+0] + w4*ar[48+r*4+0];                       \
                    float t1 = w0*ar[ 0+r*4+1] + w1*ar[12+r*4+1] + w2*ar[24+r*4+1]      \
                             + w3*ar[36+r*4+1] + w4*ar[48+r*4+1];                       \
                    float t2 = w0*ar[ 0+r*4+2] + w1*ar[12+r*4+2] + w2*ar[24+r*4+2]      \
                             + w3*ar[36+r*4+2] + w4*ar[48+r*4+2];                       \
                    float t3 = w0*ar[ 0+r*4+3] + w1*ar[12+r*4+3] + w2*ar[24+r*4+3]      \
                             + w3*ar[36+r*4+3] + w4*ar[48+r*4+3];                       \
                    y[r] = t0*px + t1*py + t2*pz + t3;                                  \
                }                                                                       \
                vtT[(c0+0) * S_VT + rl] = y[0];                                         \
                vtT[(c0+1) * S_VT + rl] = y[1];                                         \
                vtT[(c0+2) * S_VT + rl] = y[2];                                         \
            }                                                                           \
        }                                                                               \
        BAR_LGKM();                                                                     \
        /* transpose out: per row, 3 coalesced dword stores of 64 cols each */          \
        {                                                                               \
            const bool full = (ntile * 192 + 192 <= N3);                                \
            for (int rr = wn; rr < 16; rr += 4) {                                       \
                size_t ob = (size_t)(b0 + HH * 16 + rr) * N3 + (size_t)ntile * 192;     \
                if (full) {                                                             \
                    _Pragma("unroll")                                                   \
                    for (int e = 0; e < 3; ++e) {                                       \
                        int col = e * 64 + lane;                                        \
                        out[ob + col] = vtT[col * S_VT + rr];                           \
                    }                                                                   \
                } else {                                                                \
                    _Pragma("unroll")                                                   \
                    for (int e = 0; e < 3; ++e) {                                       \
                        int col = e * 64 + lane;                                        \
                        if (ntile * 192 + col < N3)                                     \
                            out[ob + col] = vtT[col * S_VT + rr];                       \
                    }                                                                   \
                }                                                                       \
            }                                                                           \
        }                                                                               \
    }

    EPI_PHASE(0, arA,
        { _Pragma("unroll")
          for (int u = 0; u < 4; ++u) {
              int i = u * 256 + t;
              arB[u] = (i < 960) ? AtrG[(size_t)(b0 + 16) * 60 + i] : 0.f;
          } } )
    EPI_PHASE(1, arB, { } )
    #undef EPI_PHASE
}

extern "C" void kernel_launch(void* const* d_in, const int* in_sizes, int n_in,
                              void* d_out, int out_size, void* d_ws, size_t ws_size,
                              hipStream_t stream) {
    const float* shp  = (const float*)d_in[0];
    const float* expn = (const float*)d_in[1];
    const float* neck = (const float*)d_in[2];
    const float* jaw  = (const float*)d_in[3];
    const float* eye  = (const float*)d_in[4];
    const float* vt   = (const float*)d_in[5];
    const float* sdir = (const float*)d_in[6];
    const float* pdir = (const float*)d_in[7];
    const float* jreg = (const float*)d_in[8];
    const float* lbsw = (const float*)d_in[9];
    char* ws  = (char*)d_ws;
    float* out = (float*)d_out;

    hipMemsetAsync(ws + WS_JD_B, 0, 2272 * 4, stream);
    k_prep <<<GP_J + GP_S + GP_P, 256, 0, stream>>>(jreg, sdir, vt, pdir, ws);
    k_batch<<<32, 256, 0, stream>>>(shp, expn, neck, jaw, eye, ws);
    k_mega <<<dim3(64, NTIL), 256, 0, stream>>>(ws, vt, lbsw, out);
}